// Round 3
// baseline (599.826 us; speedup 1.0000x reference)
//
#include <hip/hip_runtime.h>
#include <math.h>

typedef _Float16 h16;
typedef _Float16 half8 __attribute__((ext_vector_type(8)));
typedef float f32x4 __attribute__((ext_vector_type(4)));

#define BATCH 16
#define CH 256
#define EPSBN 1e-5f

constexpr size_t WE_STRIDE = (size_t)CH * CH * 9;   // 589,824 elems per expert
constexpr int XREG = 3176;   // halves per ci-octet x region: (6*66+1 pad)*8 -> quad regions shift banks
constexpr int WREG = 292;    // halves per co row of w LDS: 9 taps*32ci + 4 pad -> l15*18 bank walk, uniform

__device__ __forceinline__ float silu_(float v) {
    return v * (1.0f / (1.0f + __expf(-v)));
}

// Implicit-GEMM 3x3 conv (pad 1) over NHWC f16 input, 9 tap-shifted GEMMs.
// Block tile: 256 sp (4 rows) x 64 co; 4 waves, wave = 1 row (64 sp) x 64 co
// = 4x4 fragments. BOTH operands staged in LDS (x: 6 halo rows x 66 x 32ci;
// w: 64 co x 9 taps x 32 ci, co-stride 292 halves -> bank-uniform reads).
// Compute phase is pure ds_read+MFMA (no vmcnt waits on the critical path) --
// the previous versions' per-tap global weight loads pinned MfmaUtil at 17%.
// Weight panel is also staged once per block (vs read per wave): 4x less L2.
// XCD swizzle keeps each XCD's working set (2 bz) L2/L3-local.
// MFMA contract (m89/m91): A[m=l15][k=quad*8+j], B[k=quad*8+j][n=l15], D[m=quad*4+r][n=l15]
// MODE 0: out = y f16 NHWC, BN+SiLU.       acc[i*4+j]: i=sp frag, j=co frag
// MODE 1: out fp32 NCHW, resid+BN+SiLU.    acc[i*4+j]: i=co frag, j=sp frag
template<int MODE>
__global__ __launch_bounds__(256, 2)
void conv_mfma(const h16* __restrict__ xin,
               const h16* __restrict__ wt,
               const float* __restrict__ bng, const float* __restrict__ bnb,
               const float* __restrict__ bnm, const float* __restrict__ bnv,
               const float* __restrict__ resid,
               void* __restrict__ outv)
{
    __shared__ h16 xt[4 * XREG];     // 25,408 B
    __shared__ h16 wlds[64 * WREG];  // 37,376 B   (total 62,784 B -> 2 blocks/CU)

    const int t = threadIdx.x;
    // bijective XCD swizzle: 1024 blocks, 8 XCDs -> 128 consecutive swz per XCD
    // per XCD: all 16 sp-tiles x 4 co-tiles x 2 bz -> weights+y L2-resident
    const int swz = (blockIdx.x & 7) * 128 + (blockIdx.x >> 3);
    const int bx  = swz & 15;        // 16 spatial tiles (4 rows each)
    const int gy  = swz >> 4;
    const int by  = gy & 3;          // 4 co tiles
    const int bz  = gy >> 2;         // batch
    const int h0  = bx * 4;
    const int co0 = by * 64;
    const int ws   = t >> 6;         // wave's output row: h0 + ws
    const int lane = t & 63;
    const int quad = lane >> 4;
    const int l15  = lane & 15;

    f32x4 acc[16];
    #pragma unroll
    for (int i = 0; i < 16; ++i) {
        f32x4 z = {0.f, 0.f, 0.f, 0.f};
        acc[i] = z;
    }

    // weight staging: thread t owns co = t>>2, ci-octet cig = t&3, all 9 taps.
    // global wt layout [.. tap][co][ci]; 4 consecutive threads read 64 B contiguous.
    const h16* wbase = wt + ((MODE == 1) ? (size_t)bz * 9 * 65536 : (size_t)0);
    const int wgoff = (co0 + (t >> 2)) * 256 + (t & 3) * 8;
    const int wlofs = (t >> 2) * WREG + (t & 3) * 8;

    // x staging descriptors: 1584 half8 tasks (6 halo rows x 66 cols x 4 ci-octets),
    // cig-minor so 4 consecutive threads read 64 B contiguous global.
    const h16* xb = xin + ((size_t)bz << 20);   // bz*64*64*256
    int goff[7], lofs[7];
    #pragma unroll
    for (int k = 0; k < 7; ++k) {
        int idx = t + k * 256;
        goff[k] = -1;
        lofs[k] = -1;
        if (idx < 1584) {
            int cig = idx & 3;
            int sp  = idx >> 2;            // row*66+col, 0..395
            int row = sp / 66;
            int col = sp - row * 66;
            int gh = h0 - 1 + row, gw = col - 1;
            lofs[k] = cig * XREG + sp * 8;
            if ((unsigned)gh < 64u && (unsigned)gw < 64u)
                goff[k] = ((gh << 6) + gw) * 256 + cig * 8;
        }
    }

    const h16* xq = xt + quad * XREG + l15 * 8;
    const h16* wq = wlds + l15 * WREG + quad * 8;

    for (int c = 0; c < 8; ++c) {
        const int ci0 = c * 32;
        __syncthreads();
        // stage weights: 9 taps x 64 co x 32 ci = 36,864 B
        {
            const h16* wg = wbase + wgoff + ci0;
            h16* wl = wlds + wlofs;
            #pragma unroll
            for (int k = 0; k < 9; ++k)
                *(half8*)(wl + k * 32) = *(const half8*)(wg + (size_t)k * 65536);
        }
        // stage x: 6 halo rows x 66 cols x 32 ci = 25,344 B
        #pragma unroll
        for (int k = 0; k < 7; ++k) {
            if (lofs[k] >= 0) {
                half8 v = {0, 0, 0, 0, 0, 0, 0, 0};
                if (goff[k] >= 0) v = *(const half8*)(xb + goff[k] + ci0);
                *(half8*)(xt + lofs[k]) = v;
            }
        }
        __syncthreads();

        #pragma unroll
        for (int kh = 0; kh < 3; ++kh)
        #pragma unroll
        for (int kw = 0; kw < 3; ++kw) {
            const int tap = kh * 3 + kw;
            half8 wf[4], xf[4];
            #pragma unroll
            for (int f = 0; f < 4; ++f)
                wf[f] = *(const half8*)(wq + f * 16 * WREG + tap * 32);
            #pragma unroll
            for (int i = 0; i < 4; ++i)
                xf[i] = *(const half8*)(xq + ((ws + kh) * 66 + i * 16 + kw) * 8);
            if (MODE == 0) {
                #pragma unroll
                for (int i = 0; i < 4; ++i)
                    #pragma unroll
                    for (int j = 0; j < 4; ++j)
                        acc[i * 4 + j] = __builtin_amdgcn_mfma_f32_16x16x32_f16(
                            xf[i], wf[j], acc[i * 4 + j], 0, 0, 0);
            } else {
                #pragma unroll
                for (int i = 0; i < 4; ++i)
                    #pragma unroll
                    for (int j = 0; j < 4; ++j)
                        acc[i * 4 + j] = __builtin_amdgcn_mfma_f32_16x16x32_f16(
                            wf[i], xf[j], acc[i * 4 + j], 0, 0, 0);
            }
        }
    }

    if (MODE == 0) {
        // D[sp][co] -> y f16 NHWC, BN+SiLU. wave writes row h0+ws, 64 cos
        h16* yout = (h16*)outv;
        float sc[4], sh[4];
        #pragma unroll
        for (int j = 0; j < 4; ++j) {
            int cch = co0 + j * 16 + l15;
            float s = bng[cch] * rsqrtf(bnv[cch] + EPSBN);
            sc[j] = s; sh[j] = bnb[cch] - bnm[cch] * s;
        }
        const int h = h0 + ws;
        #pragma unroll
        for (int i = 0; i < 4; ++i)
            #pragma unroll
            for (int r = 0; r < 4; ++r) {
                int w = i * 16 + quad * 4 + r;
                size_t base = (((size_t)(bz * 64 + h) << 6) + w) * 256
                            + co0 + l15;
                #pragma unroll
                for (int j = 0; j < 4; ++j) {
                    float v = acc[i * 4 + j][r] * sc[j] + sh[j];
                    yout[base + j * 16] = (h16)silu_(v);
                }
            }
    } else {
        // D[co][sp] -> out fp32 NCHW, resid + BN+SiLU
        float* outp = (float*)outv;
        const int h = h0 + ws;
        #pragma unroll
        for (int i = 0; i < 4; ++i) {
            float sc[4], sh[4];
            #pragma unroll
            for (int r = 0; r < 4; ++r) {
                int cch = co0 + i * 16 + quad * 4 + r;
                float s = bng[cch] * rsqrtf(bnv[cch] + EPSBN);
                sc[r] = s; sh[r] = bnb[cch] - bnm[cch] * s;
            }
            #pragma unroll
            for (int j = 0; j < 4; ++j) {
                int w = j * 16 + l15;
                #pragma unroll
                for (int r = 0; r < 4; ++r) {
                    int cch = co0 + i * 16 + quad * 4 + r;
                    size_t idx = ((size_t)(bz * CH + cch) << 12) + (h << 6) + w;
                    float v = acc[i * 4 + j][r] * sc[r] + sh[r];
                    outp[idx] = resid[idx] + silu_(v);
                }
            }
        }
    }
}

// x fp32 NCHW -> xh f16 NHWC (LDS-tiled transpose). Block = (cg 64-ch group, h, b).
__global__ __launch_bounds__(256)
void prep_x(const float* __restrict__ x, h16* __restrict__ xh) {
    __shared__ float lt[64][65];
    int cg = blockIdx.x, h = blockIdx.y, b = blockIdx.z;
    int t = threadIdx.x;
    {
        int cl = t >> 2, wq = t & 3;
        const float4* src = (const float4*)(x + (((size_t)(b * CH + cg * 64 + cl)) << 12)
                                              + ((size_t)h << 6));
        #pragma unroll
        for (int k = 0; k < 4; ++k) {
            int w4 = wq + k * 4;
            float4 v = src[w4];
            lt[cl][w4 * 4 + 0] = v.x;
            lt[cl][w4 * 4 + 1] = v.y;
            lt[cl][w4 * 4 + 2] = v.z;
            lt[cl][w4 * 4 + 3] = v.w;
        }
    }
    __syncthreads();
    {
        int wl = t >> 2, cq = t & 3;
        half8 a2[2];
        h16* ap = (h16*)a2;
        #pragma unroll
        for (int m = 0; m < 16; ++m) ap[m] = (h16)lt[cq * 16 + m][wl];
        size_t base = ((((size_t)(b * 64 + h)) << 6) + wl) * 256 + cg * 64 + cq * 16;
        *(half8*)(xh + base)     = a2[0];
        *(half8*)(xh + base + 8) = a2[1];
    }
}

// w1 [co][ci][9] fp32 -> w1t [tap][co][ci] f16
__global__ void prep_w1(const float* __restrict__ w1, h16* __restrict__ w1t) {
    int pair = blockIdx.x * 256 + threadIdx.x;   // co*256+ci
    #pragma unroll
    for (int tap = 0; tap < 9; ++tap)
        w1t[((size_t)tap << 16) + pair] = (h16)w1[(size_t)pair * 9 + tap];
}

// part[slice][b][c] = partial sum over 256 sp of y NHWC (vectorized, no atomics)
__global__ __launch_bounds__(256)
void pool_kernel(const h16* __restrict__ y, float* __restrict__ part) {
    __shared__ float red[8][256];
    int slice = blockIdx.x, b = blockIdx.y;
    int t = threadIdx.x;
    int oct = t & 31, ss = t >> 5;
    float a[8];
    #pragma unroll
    for (int k = 0; k < 8; ++k) a[k] = 0.f;
    const h16* p = y + ((size_t)(b * 4096 + slice * 256 + ss)) * 256 + oct * 8;
    #pragma unroll 4
    for (int i = 0; i < 32; ++i) {
        half8 v = *(const half8*)(p + (size_t)i * 8 * 256);
        #pragma unroll
        for (int k = 0; k < 8; ++k) a[k] += (float)v[k];
    }
    #pragma unroll
    for (int k = 0; k < 8; ++k) red[ss][oct * 8 + k] = a[k];
    __syncthreads();
    float s = 0.f;
    #pragma unroll
    for (int q = 0; q < 8; ++q) s += red[q][t];
    part[((size_t)slice * BATCH + b) * 256 + t] = s;
}

__global__ void routing_kernel(const float* __restrict__ part,
                               const float* __restrict__ wr,
                               const float* __restrict__ br,
                               float* __restrict__ routing) {
    int t = threadIdx.x;
    if (t < 64) {
        int b = t >> 2, e = t & 3;
        float s = 0.f;
        for (int c = 0; c < 256; ++c) {
            float p = 0.f;
            for (int sl = 0; sl < 16; ++sl)
                p += part[((size_t)sl * BATCH + b) * 256 + c];
            s += p * wr[e * 256 + c];
        }
        s = s * (1.f / 4096.f) + br[e];
        routing[t] = 1.f / (1.f + __expf(-s));
    }
}

// wt2[b][tap][co][ci] f16 = sum_e routing[b][e] * w_e[e][(co*256+ci)*9+tap]
// w_e staged through LDS so global reads are float4-coalesced.
__global__ __launch_bounds__(256)
void kern_gen(const float* __restrict__ w_e,
              const float* __restrict__ routing,
              h16* __restrict__ wt2) {
    __shared__ float lw[4 * 2304];   // 36,864 B
    __shared__ float rsh[64];
    int t = threadIdx.x;
    int pair0 = blockIdx.x * 256;
    if (t < 64) rsh[t] = routing[t];
    #pragma unroll
    for (int e = 0; e < 4; ++e) {
        const float4* src = (const float4*)(w_e + (size_t)e * WE_STRIDE + (size_t)pair0 * 9);
        #pragma unroll
        for (int k = 0; k < 3; ++k) {
            int idx = t + k * 256;
            if (idx < 576) {
                float4 v = src[idx];
                float* d = &lw[e * 2304 + idx * 4];
                d[0] = v.x; d[1] = v.y; d[2] = v.z; d[3] = v.w;
            }
        }
    }
    __syncthreads();
    float wv[4][9];
    #pragma unroll
    for (int e = 0; e < 4; ++e)
        #pragma unroll
        for (int k = 0; k < 9; ++k)
            wv[e][k] = lw[e * 2304 + t * 9 + k];
    for (int b = 0; b < 16; ++b) {
        float r0 = rsh[b * 4 + 0], r1 = rsh[b * 4 + 1];
        float r2 = rsh[b * 4 + 2], r3 = rsh[b * 4 + 3];
        #pragma unroll
        for (int tap = 0; tap < 9; ++tap) {
            float s = r0 * wv[0][tap] + r1 * wv[1][tap]
                    + r2 * wv[2][tap] + r3 * wv[3][tap];
            wt2[((size_t)(b * 9 + tap) << 16) + pair0 + t] = (h16)s;
        }
    }
}

extern "C" void kernel_launch(void* const* d_in, const int* in_sizes, int n_in,
                              void* d_out, int out_size, void* d_ws, size_t ws_size,
                              hipStream_t stream) {
    const float* x    = (const float*)d_in[0];
    const float* w1   = (const float*)d_in[1];
    const float* bn1g = (const float*)d_in[2];
    const float* bn1b = (const float*)d_in[3];
    const float* bn1m = (const float*)d_in[4];
    const float* bn1v = (const float*)d_in[5];
    const float* wr   = (const float*)d_in[6];
    const float* br   = (const float*)d_in[7];
    const float* w_e  = (const float*)d_in[8];
    const float* bn2g = (const float*)d_in[9];
    const float* bn2b = (const float*)d_in[10];
    const float* bn2m = (const float*)d_in[11];
    const float* bn2v = (const float*)d_in[12];

    char* w = (char*)d_ws;
    h16*   xh      = (h16*)(w);                   // 33,554,432 B (x as f16 NHWC)
    h16*   y       = (h16*)(w + 33554432);        // 33,554,432 B (f16 NHWC)
    h16*   w1t     = (h16*)(w + 67108864);        //  1,179,648 B
    h16*   wt2     = (h16*)(w + 68288512);        // 18,874,368 B
    float* part    = (float*)(w + 87162880);      //    262,144 B
    float* routing = (float*)(w + 87425024);      //        256 B

    prep_x<<<dim3(4, 64, BATCH), 256, 0, stream>>>(x, xh);
    prep_w1<<<dim3(256), 256, 0, stream>>>(w1, w1t);

    dim3 cgrid(1024);   // 16 sp x 4 co x 16 bz, XCD-swizzled inside the kernel
    conv_mfma<0><<<cgrid, 256, 0, stream>>>(xh, w1t, bn1g, bn1b, bn1m, bn1v,
                                            nullptr, y);
    pool_kernel<<<dim3(16, BATCH), 256, 0, stream>>>(y, part);
    routing_kernel<<<dim3(1), 64, 0, stream>>>(part, wr, br, routing);
    kern_gen<<<dim3(256), 256, 0, stream>>>(w_e, routing, wt2);
    conv_mfma<1><<<cgrid, 256, 0, stream>>>(y, wt2, bn2g, bn2b, bn2m, bn2v,
                                            x, (float*)d_out);
}

// Round 4
// 552.951 us; speedup vs baseline: 1.0848x; 1.0848x over previous
//
#include <hip/hip_runtime.h>
#include <math.h>

typedef _Float16 h16;
typedef _Float16 half8 __attribute__((ext_vector_type(8)));
typedef float f32x4 __attribute__((ext_vector_type(4)));

#define BATCH 16
#define CH 256
#define EPSBN 1e-5f

constexpr size_t WE_STRIDE = (size_t)CH * CH * 9;   // 589,824 elems per expert
constexpr int RSTRIDE = 2120;       // halves per ci-octet region: 265 slots*8 (pad slot shifts banks/quad)
constexpr int BUFH    = 4 * RSTRIDE; // halves per LDS buffer (16,960 B)

__device__ __forceinline__ float silu_(float v) {
    return v * (1.0f / (1.0f + __expf(-v)));
}

// Implicit-GEMM 3x3 conv (pad 1) over NHWC f16 input, 9 tap-shifted GEMMs.
// Tile: 128 sp (2 rows) x 128 co. 4 waves in 2x2 (sp-row x co-half): wave =
// 1 row (64 sp) x 64 co = 4x4 frags. x is staged via ASYNC global_load_lds
// width-16 (no VGPR round-trip, no ds_write), double-buffered with
// prefetch-past-compute: chunk c+1's loads are issued BEFORE chunk c's MFMAs,
// and the single __syncthreads per chunk drains vmcnt after ~2800cy of
// compute -- loads are already complete (T3-minimum / m97+ structure).
// Staging is wave-linear (gload_lds dest = uniform base + lane*16, m104):
// wave wv owns ci-octet region wv; OOB halo slots are zero-filled once in
// the prologue and exec-masked out of gload_lds (positions chunk-invariant).
// Weights read per-wave from global in compute (L2-hot via XCD swizzle).
// MFMA contract (m89/m91): A[m=l15][k=quad*8+j], B[k=quad*8+j][n=l15], D[m=quad*4+r][n=l15]
// MODE 0: out = y f16 NHWC, BN+SiLU.       acc[i*4+j]: i=sp frag, j=co frag
// MODE 1: out fp32 NCHW, resid+BN+SiLU.    acc[i*4+j]: i=co frag, j=sp frag
template<int MODE>
__global__ __launch_bounds__(256, 4)
void conv_mfma(const h16* __restrict__ xin,
               const h16* __restrict__ wt,
               const float* __restrict__ bng, const float* __restrict__ bnb,
               const float* __restrict__ bnm, const float* __restrict__ bnv,
               const float* __restrict__ resid,
               void* __restrict__ outv)
{
    __shared__ h16 xt[2 * BUFH];   // 33,920 B double-buffered -> 4 blocks/CU

    const int t = threadIdx.x;
    // bijective XCD swizzle: 1024 blocks, 8 XCDs -> 128 consecutive swz per XCD
    const int swz = (blockIdx.x & 7) * 128 + (blockIdx.x >> 3);
    const int bx  = swz & 31;        // 32 spatial tiles (2 rows each)
    const int gy  = swz >> 5;
    const int by  = gy & 1;          // 2 co tiles
    const int bz  = gy >> 1;         // batch
    const int h0  = bx * 2;
    const int co0 = by * 128;
    const int wv   = t >> 6;
    const int ws   = wv >> 1;        // wave's output row: h0 + ws
    const int wc   = wv & 1;         // wave's co half: co0 + wc*64
    const int lane = t & 63;
    const int quad = lane >> 4;
    const int l15  = lane & 15;

    f32x4 acc[16];
    #pragma unroll
    for (int i = 0; i < 16; ++i) {
        f32x4 z = {0.f, 0.f, 0.f, 0.f};
        acc[i] = z;
    }

    // lane weight base: co = co0 + wc*64 + f*16 + l15, ci = ci0 + quad*8
    const h16* wrow = wt + ((MODE == 1) ? (size_t)bz * 9 * 65536 : (size_t)0)
                         + ((size_t)(co0 + wc * 64 + l15) << 8)
                         + (size_t)(quad * 8);

    // staging: wave wv fills ci-octet region wv. slot = k*64+lane in [0,264):
    // sp = row*66+col over 4 halo rows x 66 halo cols. goff = per-lane global
    // h16 offset (valid >= 0), -1 for OOB / beyond-264 lanes.
    const h16* xb = xin + ((size_t)bz << 20);   // bz*64*64*256
    int goff[5];
    #pragma unroll
    for (int k = 0; k < 5; ++k) {
        int slot = k * 64 + lane;
        int row = slot / 66;
        int col = slot - row * 66;
        int gh = h0 - 1 + row, gw = col - 1;
        goff[k] = -1;
        if (slot < 264 && (unsigned)gh < 64u && (unsigned)gw < 64u)
            goff[k] = ((gh << 6) + gw) * 256 + wv * 8;
    }

    // zero-fill OOB slots in BOTH buffers once (chunk-invariant positions;
    // gload_lds is exec-masked off these slots forever after).
    {
        half8 z = {0, 0, 0, 0, 0, 0, 0, 0};
        #pragma unroll
        for (int k = 0; k < 5; ++k) {
            int slot = k * 64 + lane;
            if (slot < 264 && goff[k] < 0) {
                *(half8*)(xt + wv * RSTRIDE + slot * 8) = z;
                *(half8*)(xt + BUFH + wv * RSTRIDE + slot * 8) = z;
            }
        }
    }

    // async stage chunk (ci0) into buffer b: 5 wave-level gload_lds x16B,
    // dest = uniform(region base + k*64 slots) + lane*16 (linear, m104).
    auto stage = [&](int b, int ci0) {
        const h16* g = xb + ci0;
        #pragma unroll
        for (int k = 0; k < 5; ++k) {
            if (goff[k] >= 0)
                __builtin_amdgcn_global_load_lds(
                    (const __attribute__((address_space(1))) void*)(g + goff[k]),
                    (__attribute__((address_space(3))) void*)(xt + b * BUFH + wv * RSTRIDE + k * 512),
                    16, 0, 0);
        }
    };

    stage(0, 0);
    __syncthreads();

    for (int c = 0; c < 8; ++c) {
        if (c < 7) stage((c + 1) & 1, (c + 1) * 32);   // prefetch next chunk

        const h16* xq  = xt + (c & 1) * BUFH + quad * RSTRIDE + l15 * 8;
        const h16* wcp = wrow + c * 32;
        #pragma unroll
        for (int kh = 0; kh < 3; ++kh)
        #pragma unroll
        for (int kw = 0; kw < 3; ++kw) {
            const int tap = kh * 3 + kw;
            half8 wf[4], xf[4];
            #pragma unroll
            for (int f = 0; f < 4; ++f)
                wf[f] = *(const half8*)(wcp + (size_t)tap * 65536 + f * 4096);
            #pragma unroll
            for (int i = 0; i < 4; ++i)
                xf[i] = *(const half8*)(xq + ((ws + kh) * 66 + i * 16 + kw) * 8);
            if (MODE == 0) {
                #pragma unroll
                for (int i = 0; i < 4; ++i)
                    #pragma unroll
                    for (int j = 0; j < 4; ++j)
                        acc[i * 4 + j] = __builtin_amdgcn_mfma_f32_16x16x32_f16(
                            xf[i], wf[j], acc[i * 4 + j], 0, 0, 0);
            } else {
                #pragma unroll
                for (int i = 0; i < 4; ++i)
                    #pragma unroll
                    for (int j = 0; j < 4; ++j)
                        acc[i * 4 + j] = __builtin_amdgcn_mfma_f32_16x16x32_f16(
                            wf[i], xf[j], acc[i * 4 + j], 0, 0, 0);
            }
        }
        __syncthreads();   // drains vmcnt: prefetched loads had full compute to land
    }

    if (MODE == 0) {
        // D[sp][co] -> y f16 NHWC, BN+SiLU. wave writes row h0+ws, cos wc*64..+63
        h16* yout = (h16*)outv;
        float sc[4], sh[4];
        #pragma unroll
        for (int j = 0; j < 4; ++j) {
            int cch = co0 + wc * 64 + j * 16 + l15;
            float s = bng[cch] * rsqrtf(bnv[cch] + EPSBN);
            sc[j] = s; sh[j] = bnb[cch] - bnm[cch] * s;
        }
        const int h = h0 + ws;
        #pragma unroll
        for (int i = 0; i < 4; ++i)
            #pragma unroll
            for (int r = 0; r < 4; ++r) {
                int w = i * 16 + quad * 4 + r;
                size_t base = (((size_t)(bz * 64 + h) << 6) + w) * 256
                            + co0 + wc * 64 + l15;
                #pragma unroll
                for (int j = 0; j < 4; ++j) {
                    float v = acc[i * 4 + j][r] * sc[j] + sh[j];
                    yout[base + j * 16] = (h16)silu_(v);
                }
            }
    } else {
        // D[co][sp] -> out fp32 NCHW, resid + BN+SiLU
        float* outp = (float*)outv;
        const int h = h0 + ws;
        #pragma unroll
        for (int i = 0; i < 4; ++i) {
            float sc[4], sh[4];
            #pragma unroll
            for (int r = 0; r < 4; ++r) {
                int cch = co0 + wc * 64 + i * 16 + quad * 4 + r;
                float s = bng[cch] * rsqrtf(bnv[cch] + EPSBN);
                sc[r] = s; sh[r] = bnb[cch] - bnm[cch] * s;
            }
            #pragma unroll
            for (int j = 0; j < 4; ++j) {
                int w = j * 16 + l15;
                #pragma unroll
                for (int r = 0; r < 4; ++r) {
                    int cch = co0 + wc * 64 + i * 16 + quad * 4 + r;
                    size_t idx = ((size_t)(bz * CH + cch) << 12) + (h << 6) + w;
                    float v = acc[i * 4 + j][r] * sc[r] + sh[r];
                    outp[idx] = resid[idx] + silu_(v);
                }
            }
        }
    }
}

// x fp32 NCHW -> xh f16 NHWC (LDS-tiled transpose). Block = (cg 64-ch group, h, b).
__global__ __launch_bounds__(256)
void prep_x(const float* __restrict__ x, h16* __restrict__ xh) {
    __shared__ float lt[64][65];
    int cg = blockIdx.x, h = blockIdx.y, b = blockIdx.z;
    int t = threadIdx.x;
    {
        int cl = t >> 2, wq = t & 3;
        const float4* src = (const float4*)(x + (((size_t)(b * CH + cg * 64 + cl)) << 12)
                                              + ((size_t)h << 6));
        #pragma unroll
        for (int k = 0; k < 4; ++k) {
            int w4 = wq + k * 4;
            float4 v = src[w4];
            lt[cl][w4 * 4 + 0] = v.x;
            lt[cl][w4 * 4 + 1] = v.y;
            lt[cl][w4 * 4 + 2] = v.z;
            lt[cl][w4 * 4 + 3] = v.w;
        }
    }
    __syncthreads();
    {
        int wl = t >> 2, cq = t & 3;
        half8 a2[2];
        h16* ap = (h16*)a2;
        #pragma unroll
        for (int m = 0; m < 16; ++m) ap[m] = (h16)lt[cq * 16 + m][wl];
        size_t base = ((((size_t)(b * 64 + h)) << 6) + wl) * 256 + cg * 64 + cq * 16;
        *(half8*)(xh + base)     = a2[0];
        *(half8*)(xh + base + 8) = a2[1];
    }
}

// w1 [co][ci][9] fp32 -> w1t [tap][co][ci] f16
__global__ void prep_w1(const float* __restrict__ w1, h16* __restrict__ w1t) {
    int pair = blockIdx.x * 256 + threadIdx.x;   // co*256+ci
    #pragma unroll
    for (int tap = 0; tap < 9; ++tap)
        w1t[((size_t)tap << 16) + pair] = (h16)w1[(size_t)pair * 9 + tap];
}

// part[slice][b][c] = partial sum over 256 sp of y NHWC (vectorized, no atomics)
__global__ __launch_bounds__(256)
void pool_kernel(const h16* __restrict__ y, float* __restrict__ part) {
    __shared__ float red[8][256];
    int slice = blockIdx.x, b = blockIdx.y;
    int t = threadIdx.x;
    int oct = t & 31, ss = t >> 5;
    float a[8];
    #pragma unroll
    for (int k = 0; k < 8; ++k) a[k] = 0.f;
    const h16* p = y + ((size_t)(b * 4096 + slice * 256 + ss)) * 256 + oct * 8;
    #pragma unroll 4
    for (int i = 0; i < 32; ++i) {
        half8 v = *(const half8*)(p + (size_t)i * 8 * 256);
        #pragma unroll
        for (int k = 0; k < 8; ++k) a[k] += (float)v[k];
    }
    #pragma unroll
    for (int k = 0; k < 8; ++k) red[ss][oct * 8 + k] = a[k];
    __syncthreads();
    float s = 0.f;
    #pragma unroll
    for (int q = 0; q < 8; ++q) s += red[q][t];
    part[((size_t)slice * BATCH + b) * 256 + t] = s;
}

__global__ void routing_kernel(const float* __restrict__ part,
                               const float* __restrict__ wr,
                               const float* __restrict__ br,
                               float* __restrict__ routing) {
    int t = threadIdx.x;
    if (t < 64) {
        int b = t >> 2, e = t & 3;
        float s = 0.f;
        for (int c = 0; c < 256; ++c) {
            float p = 0.f;
            for (int sl = 0; sl < 16; ++sl)
                p += part[((size_t)sl * BATCH + b) * 256 + c];
            s += p * wr[e * 256 + c];
        }
        s = s * (1.f / 4096.f) + br[e];
        routing[t] = 1.f / (1.f + __expf(-s));
    }
}

// wt2[b][tap][co][ci] f16 = sum_e routing[b][e] * w_e[e][(co*256+ci)*9+tap]
// w_e staged through LDS so global reads are float4-coalesced.
__global__ __launch_bounds__(256)
void kern_gen(const float* __restrict__ w_e,
              const float* __restrict__ routing,
              h16* __restrict__ wt2) {
    __shared__ float lw[4 * 2304];   // 36,864 B
    __shared__ float rsh[64];
    int t = threadIdx.x;
    int pair0 = blockIdx.x * 256;
    if (t < 64) rsh[t] = routing[t];
    #pragma unroll
    for (int e = 0; e < 4; ++e) {
        const float4* src = (const float4*)(w_e + (size_t)e * WE_STRIDE + (size_t)pair0 * 9);
        #pragma unroll
        for (int k = 0; k < 3; ++k) {
            int idx = t + k * 256;
            if (idx < 576) {
                float4 v = src[idx];
                float* d = &lw[e * 2304 + idx * 4];
                d[0] = v.x; d[1] = v.y; d[2] = v.z; d[3] = v.w;
            }
        }
    }
    __syncthreads();
    float wv[4][9];
    #pragma unroll
    for (int e = 0; e < 4; ++e)
        #pragma unroll
        for (int k = 0; k < 9; ++k)
            wv[e][k] = lw[e * 2304 + t * 9 + k];
    for (int b = 0; b < 16; ++b) {
        float r0 = rsh[b * 4 + 0], r1 = rsh[b * 4 + 1];
        float r2 = rsh[b * 4 + 2], r3 = rsh[b * 4 + 3];
        #pragma unroll
        for (int tap = 0; tap < 9; ++tap) {
            float s = r0 * wv[0][tap] + r1 * wv[1][tap]
                    + r2 * wv[2][tap] + r3 * wv[3][tap];
            wt2[((size_t)(b * 9 + tap) << 16) + pair0 + t] = (h16)s;
        }
    }
}

extern "C" void kernel_launch(void* const* d_in, const int* in_sizes, int n_in,
                              void* d_out, int out_size, void* d_ws, size_t ws_size,
                              hipStream_t stream) {
    const float* x    = (const float*)d_in[0];
    const float* w1   = (const float*)d_in[1];
    const float* bn1g = (const float*)d_in[2];
    const float* bn1b = (const float*)d_in[3];
    const float* bn1m = (const float*)d_in[4];
    const float* bn1v = (const float*)d_in[5];
    const float* wr   = (const float*)d_in[6];
    const float* br   = (const float*)d_in[7];
    const float* w_e  = (const float*)d_in[8];
    const float* bn2g = (const float*)d_in[9];
    const float* bn2b = (const float*)d_in[10];
    const float* bn2m = (const float*)d_in[11];
    const float* bn2v = (const float*)d_in[12];

    char* w = (char*)d_ws;
    h16*   xh      = (h16*)(w);                   // 33,554,432 B (x as f16 NHWC)
    h16*   y       = (h16*)(w + 33554432);        // 33,554,432 B (f16 NHWC)
    h16*   w1t     = (h16*)(w + 67108864);        //  1,179,648 B
    h16*   wt2     = (h16*)(w + 68288512);        // 18,874,368 B
    float* part    = (float*)(w + 87162880);      //    262,144 B
    float* routing = (float*)(w + 87425024);      //        256 B

    prep_x<<<dim3(4, 64, BATCH), 256, 0, stream>>>(x, xh);
    prep_w1<<<dim3(256), 256, 0, stream>>>(w1, w1t);

    dim3 cgrid(1024);   // 32 sp x 2 co x 16 bz, XCD-swizzled inside the kernel
    conv_mfma<0><<<cgrid, 256, 0, stream>>>(xh, w1t, bn1g, bn1b, bn1m, bn1v,
                                            nullptr, y);
    pool_kernel<<<dim3(16, BATCH), 256, 0, stream>>>(y, part);
    routing_kernel<<<dim3(1), 64, 0, stream>>>(part, wr, br, routing);
    kern_gen<<<dim3(256), 256, 0, stream>>>(w_e, routing, wt2);
    conv_mfma<1><<<cgrid, 256, 0, stream>>>(y, wt2, bn2g, bn2b, bn2m, bn2v,
                                            x, (float*)d_out);
}